// Round 6
// baseline (163.615 us; speedup 1.0000x reference)
//
#include <hip/hip_runtime.h>
#include <hip/hip_bf16.h>

#define EPSF 1e-8f
#define GAINF 0.014731391274719739f   // 1/sqrt(512*9)

typedef __attribute__((ext_vector_type(8))) __bf16 bf16x8;
typedef __attribute__((ext_vector_type(4))) __bf16 bf16x4;
typedef __attribute__((ext_vector_type(16))) float f32x16;

// async 16B global->LDS DMA; LDS dest = wave-uniform base + lane*16
#define GLOAD_LDS16(gp, lp) __builtin_amdgcn_global_load_lds( \
    (const __attribute__((address_space(1))) unsigned int*)(gp), \
    (__attribute__((address_space(3))) unsigned int*)(lp), 16, 0, 0)

// ---------------- K_pack: x*style -> xs bf16, + border zero ------------------
// xs layout: [b][cb16][site1156][32ch] bf16   (site = y*34+x, padded 34x34)
// Split from the old fused k_prep for per-dispatch counters. Load phase uses
// float4 (4 instrs/thread vs 16 scalar); store phase emits bf16x8 (16B) with
// a lane mapping giving 2-way (free) LDS banking on the pad-65 tile.
__global__ void k_pack(const float* __restrict__ x, const float* __restrict__ style,
                       __hip_bfloat16* __restrict__ xs) {
  int blk = blockIdx.x, tid = threadIdx.x;
  if (blk < 2048) {
    __shared__ float tile[64][65];
    int b = blk >> 7, rem = blk & 127, ct = rem >> 4, pt = rem & 15;
    int p0 = pt * 64, c0 = ct * 64;
    // load: thread (ci 64, xq 4); float4 per k; lanes xq contiguous 64B
    int ci = tid >> 2, xq = tid & 3;
    const float* xrow = x + (size_t)((b * 512) + (c0 + ci)) * 1024 + p0;
#pragma unroll
    for (int k = 0; k < 4; ++k) {
      int fc = k * 4 + xq;
      float4 v = *reinterpret_cast<const float4*>(xrow + fc * 4);
      tile[ci][fc * 4 + 0] = v.x;
      tile[ci][fc * 4 + 1] = v.y;
      tile[ci][fc * 4 + 2] = v.z;
      tile[ci][fc * 4 + 3] = v.w;
    }
    __syncthreads();
    // store: thread (u 8 = cbL*4+oct, px 32); 2 iters; 16B bf16x8 stores.
    // banks: addr%32 = (c + px)%32 with c in {0,8,..,56}+j -> each bank 2x (free)
    int u = tid & 7, px = tid >> 3;
    int cbL = u >> 2, oct = u & 3;
    int c_local = cbL * 32 + oct * 8;
    int cb = ct * 2 + cbL;
    float st[8];
#pragma unroll
    for (int j = 0; j < 8; ++j) st[j] = style[b * 512 + c0 + c_local + j];
#pragma unroll
    for (int it = 0; it < 2; ++it) {
      int pxe = px + it * 32;
      int p = p0 + pxe;
      int y = p >> 5, xx = p & 31;
      int site = (y + 1) * 34 + (xx + 1);
      bf16x8 v;
#pragma unroll
      for (int j = 0; j < 8; ++j)
        v[j] = (__bf16)(tile[c_local + j][pxe] * st[j]);
      *reinterpret_cast<bf16x8*>(xs + (size_t)(((b * 16 + cb) * 1156 + site) * 32 + oct * 8)) = v;
    }
  } else {
    // zero border: block = (b, cb); 132 sites x 32ch
    int bb = blk - 2048;
    int b = bb >> 4, cb = bb & 15;
    for (int i2 = tid; i2 < 528; i2 += 256) {  // 132 sites x 4 chunks
      int sb = i2 >> 2, q = i2 & 3;
      int yp, xp;
      if (sb < 34) { yp = 0; xp = sb; }
      else if (sb < 68) { yp = 33; xp = sb - 34; }
      else { int t2 = sb - 68; yp = 1 + (t2 >> 1); xp = (t2 & 1) * 33; }
      float4 z = {0.f, 0.f, 0.f, 0.f};
      *reinterpret_cast<float4*>(xs + (size_t)(((b * 16 + cb) * 1156 + yp * 34 + xp) * 32 + q * 8)) = z;
    }
  }
}

// ---------------- K_wsig: weight -> bf16 + esc[b,o] fused --------------------
// wbf layout: [t9][cb16][o512][32ch] bf16. One block per o.
__global__ void k_wsig(const float* __restrict__ style, const float* __restrict__ w,
                       __hip_bfloat16* __restrict__ wbf, float* __restrict__ esc) {
  __shared__ float red[4][16];
  int o = blockIdx.x, tid = threadIdx.x;
  float pacc[16];
#pragma unroll
  for (int b = 0; b < 16; ++b) pacc[b] = 0.f;
#pragma unroll
  for (int half = 0; half < 2; ++half) {
    int i = tid + half * 256;
    const float* p = w + (size_t)(o * 512 + i) * 9;
    float s = 0.f;
#pragma unroll
    for (int t = 0; t < 9; ++t) {
      float v = p[t];
      s += v * v;
      wbf[(size_t)t * 262144 + (i >> 5) * 16384 + o * 32 + (i & 31)] = __float2bfloat16(v);
    }
#pragma unroll
    for (int b = 0; b < 16; ++b) {
      float st = style[b * 512 + i];
      pacc[b] += st * st * s;
    }
  }
#pragma unroll
  for (int b = 0; b < 16; ++b)
#pragma unroll
    for (int off = 32; off; off >>= 1) pacc[b] += __shfl_down(pacc[b], off);
  int lane = tid & 63, wv2 = tid >> 6;
  if (lane == 0)
#pragma unroll
    for (int b = 0; b < 16; ++b) red[wv2][b] = pacc[b];
  __syncthreads();
  if (tid < 16) {
    float s = red[0][tid] + red[1][tid] + red[2][tid] + red[3][tid];
    esc[tid * 512 + o] = GAINF * rsqrtf(s * (GAINF * GAINF) + EPSF);
  }
}

// ---------------- K3: implicit-GEMM conv (exact v2 — best measured 76 us) ----
// Block = 256 thr = 4 waves sharing ONE staged B tile (128px n-tile,
// double-buffered, 26 KB). Wave tile 32o x 128px, acc[4]. Grid 512 =
// 2 blocks/CU -> 2 waves/SIMD. Compiler-scheduled per-tap interleave —
// three source-level restructures (asm waits, 64px tiles, dx-major dedup)
// all regressed; do not re-pin this schedule.
__global__ __launch_bounds__(256, 2) void k_conv(
    const __hip_bfloat16* __restrict__ wbf, const __hip_bfloat16* __restrict__ xs,
    const float* __restrict__ esc, float* __restrict__ out) {
  __shared__ __hip_bfloat16 ldsB[2 * 6528];  // 2 bufs x 204 sites x 32 ch
  int g = blockIdx.x;
  int xcd = g & 7, sblk = g >> 3;            // 512 blocks: 64 per XCD
  int mg = sblk >> 4;                        // 0..3 (128-o group)
  int n = xcd * 16 + (sblk & 15);            // 0..127; each XCD owns 2 images
  int b = n >> 3, nt = n & 7;
  int row0 = nt * 4;                         // padded rows row0..row0+5
  int tid = threadIdx.x;
  int wv = tid >> 6, lane = tid & 63;
  int l31 = lane & 31, lhi = lane >> 5;
  int o_base = mg * 128 + wv * 32;           // this wave's 32-o tile

  // staging: 816 chunks of 16B split 204/wave = 3 full rounds + 12 lanes
  // XOR swizzle on the global side (LDS dest must stay linear per wave)
  int roff[4];
#pragma unroll
  for (int j = 0; j < 4; ++j) {
    int idx = wv * 204 + j * 64 + lane;
    int site = idx >> 2, q0 = idx & 3;
    int qs = q0 ^ ((site >> 1) & 3);
    roff[j] = site * 32 + qs * 8;
  }

#define STAGE(cbv) do { \
    const __hip_bfloat16* _g = xs + (size_t)((b * 16 + (cbv)) * 1156 + row0 * 34) * 32; \
    __hip_bfloat16* _l = ldsB + ((cbv) & 1) * 6528 + wv * 1632 + lane * 8; \
    _Pragma("unroll") \
    for (int _j = 0; _j < 3; ++_j) GLOAD_LDS16(_g + roff[_j], _l + _j * 512); \
    if (lane < 12) GLOAD_LDS16(_g + roff[3], _l + 3 * 512); \
  } while (0)

  int wrow = (o_base + l31) * 32 + lhi * 8;
#define LOADA(dst, t_, cb_) do { \
    const __hip_bfloat16* _p = wbf + (size_t)(t_) * 262144 + (cb_) * 16384 + wrow; \
    dst[0] = *reinterpret_cast<const bf16x8*>(_p); \
    dst[1] = *reinterpret_cast<const bf16x8*>(_p + 16); \
  } while (0)

  f32x16 acc[4];
#pragma unroll
  for (int j = 0; j < 4; ++j)
#pragma unroll
    for (int e = 0; e < 16; ++e) acc[j][e] = 0.f;

  bf16x8 aC[2], aN[2];  // A frags [k2], current/next tap
  STAGE(0);
  LOADA(aC, 0, 0);

  for (int cb = 0; cb < 16; ++cb) {
    __syncthreads();              // drains stage(cb) (issued one full cb ago)
    if (cb < 15) STAGE(cb + 1);   // async into other buffer, in flight all cb
    const __hip_bfloat16* lb = ldsB + (cb & 1) * 6528;
#pragma unroll
    for (int t = 0; t < 9; ++t) {
      const int dy = t / 3, dx = t - dy * 3;
      if (cb < 15 || t < 8) {     // prefetch next tap's A (1 tap = 8 MFMAs ahead)
        int tn = (t == 8) ? 0 : t + 1;
        int cbn = (t == 8) ? cb + 1 : cb;
        LOADA(aN, tn, cbn);
      }
      int s[4], sw[4];
#pragma unroll
      for (int ns = 0; ns < 4; ++ns) {
        s[ns] = (ns + dy) * 34 + l31 + dx;
        sw[ns] = (s[ns] >> 1) & 3;
      }
#pragma unroll
      for (int k2 = 0; k2 < 2; ++k2) {
        int ko = (k2 << 1) | lhi;
        bf16x8 bf[4];
#pragma unroll
        for (int ns = 0; ns < 4; ++ns)
          bf[ns] = *reinterpret_cast<const bf16x8*>(&lb[(s[ns] * 4 + (ko ^ sw[ns])) * 8]);
#pragma unroll
        for (int ns = 0; ns < 4; ++ns)
          acc[ns] = __builtin_amdgcn_mfma_f32_32x32x16_bf16(aC[k2], bf[ns], acc[ns], 0, 0, 0);
      }
      aC[0] = aN[0];
      aC[1] = aN[1];
    }
  }
  // epilogue: C/D layout col=lane&31, row=(reg&3)+8*(reg>>2)+4*(lane>>5)
  int pxb = nt * 128 + l31;
#pragma unroll
  for (int reg = 0; reg < 16; ++reg) {
    int o = o_base + (reg & 3) + ((reg >> 2) << 3) + (lhi << 2);
    float e = esc[(b << 9) + o];
#pragma unroll
    for (int ns = 0; ns < 4; ++ns)
      out[(size_t)((b << 9) + o) * 1024 + pxb + ns * 32] = acc[ns][reg] * e;
  }
#undef STAGE
#undef LOADA
}

extern "C" void kernel_launch(void* const* d_in, const int* in_sizes, int n_in,
                              void* d_out, int out_size, void* d_ws, size_t ws_size,
                              hipStream_t stream) {
  const float* x = (const float*)d_in[0];      // [16,512,32,32]
  const float* style = (const float*)d_in[1];  // [16,512]
  const float* w = (const float*)d_in[2];      // [512,512,3,3]
  float* out = (float*)d_out;                  // [16,512,32,32]
  char* ws = (char*)d_ws;
  __hip_bfloat16* wbf = (__hip_bfloat16*)(ws);            // 9*16*512*32*2 = 4,718,592
  __hip_bfloat16* xs  = (__hip_bfloat16*)(ws + 4718592);  // 16*16*1156*32*2 = 18,939,904
  float* esc = (float*)(ws + 23658496);                   // 32,768

  hipLaunchKernelGGL(k_pack, dim3(2304), dim3(256), 0, stream, x, style, xs);
  hipLaunchKernelGGL(k_wsig, dim3(512), dim3(256), 0, stream, style, w, wbf, esc);
  hipLaunchKernelGGL(k_conv, dim3(512), dim3(256), 0, stream, wbf, xs, esc, out);
}